// Round 2
// baseline (2753.956 us; speedup 1.0000x reference)
//
#include <hip/hip_runtime.h>
#include <cstdint>
#include <cstddef>

#define NNODES 50000
#define NEDGES 800000
#define HID 128
#define NRBF 32
#define NGRAPH 500

// ---------------- embed: h[n,c] = emb[x[n],c], float4 ----------------
__global__ void embed_kernel(const int* __restrict__ x, const float* __restrict__ emb,
                             float* __restrict__ h) {
  int i = blockIdx.x * blockDim.x + threadIdx.x;
  if (i >= NNODES * 32) return;
  int node = i >> 5, c4 = (i & 31) * 4;
  *(float4*)&h[(size_t)node * HID + c4] = *(const float4*)&emb[(size_t)x[node] * HID + c4];
}

// ---------------- node GEMM: P2[node][part][c][{f,s}] interleaved ----------------
// part 0: h @ {Wf,Ws}[0:128] + bias (dst projections); part 1: rows 128:256 (src).
// Block: 256 threads, tile 64 rows x (128 cols x 2 mats), thread micro-tile 8x4x2.
__global__ __launch_bounds__(256, 2) void node_gemm2(
    const float* __restrict__ h, const float* __restrict__ Wf,
    const float* __restrict__ bf, const float* __restrict__ Ws,
    const float* __restrict__ bs, float* __restrict__ P2, int N) {
  const int part = blockIdx.y;
  const int row0 = blockIdx.x * 64;
  const float* Wfp = Wf + (size_t)part * 128 * HID;
  const float* Wsp = Ws + (size_t)part * 128 * HID;

  __shared__ __align__(16) float hsT[32][72];   // [k][node]
  __shared__ __align__(16) float wsf[32][128];  // [k][col]
  __shared__ __align__(16) float wss[32][128];

  const int tc = threadIdx.x & 31;   // cols tc*4 .. +3
  const int tr = threadIdx.x >> 5;   // rows tr*8 .. +7

  float accf[8][4], accs[8][4];
#pragma unroll
  for (int i = 0; i < 8; ++i)
#pragma unroll
    for (int j = 0; j < 4; ++j) { accf[i][j] = 0.f; accs[i][j] = 0.f; }

  for (int kc = 0; kc < HID; kc += 32) {
    // stage h tile transposed: 64 nodes x 32 k
#pragma unroll
    for (int j = 0; j < 2; ++j) {
      int i = threadIdx.x + 256 * j;  // 512 float4 slots
      int node = i >> 3;
      int kq = i & 7;
      int grow = row0 + node;
      if (grow >= N) grow = N - 1;
      const float4 v = *(const float4*)&h[(size_t)grow * HID + kc + kq * 4];
      hsT[kq * 4 + 0][node] = v.x;
      hsT[kq * 4 + 1][node] = v.y;
      hsT[kq * 4 + 2][node] = v.z;
      hsT[kq * 4 + 3][node] = v.w;
    }
    // stage weight chunks: 32 k x 128 cols, both matrices
#pragma unroll
    for (int j = 0; j < 4; ++j) {
      int i = threadIdx.x + 256 * j;  // 1024 float4 slots
      int kk = i >> 5;
      int colq = i & 31;
      *(float4*)&wsf[kk][colq * 4] = *(const float4*)&Wfp[(size_t)(kc + kk) * HID + colq * 4];
      *(float4*)&wss[kk][colq * 4] = *(const float4*)&Wsp[(size_t)(kc + kk) * HID + colq * 4];
    }
    __syncthreads();
#pragma unroll
    for (int k = 0; k < 32; ++k) {
      float4 a0 = *(const float4*)&hsT[k][tr * 8];
      float4 a1 = *(const float4*)&hsT[k][tr * 8 + 4];
      float4 bfv = *(const float4*)&wsf[k][tc * 4];
      float4 bsv = *(const float4*)&wss[k][tc * 4];
      float av[8] = {a0.x, a0.y, a0.z, a0.w, a1.x, a1.y, a1.z, a1.w};
      float bfa[4] = {bfv.x, bfv.y, bfv.z, bfv.w};
      float bsa[4] = {bsv.x, bsv.y, bsv.z, bsv.w};
#pragma unroll
      for (int i = 0; i < 8; ++i)
#pragma unroll
        for (int j = 0; j < 4; ++j) {
          accf[i][j] = fmaf(av[i], bfa[j], accf[i][j]);
          accs[i][j] = fmaf(av[i], bsa[j], accs[i][j]);
        }
    }
    __syncthreads();
  }

  float bfa[4] = {0.f, 0.f, 0.f, 0.f}, bsa[4] = {0.f, 0.f, 0.f, 0.f};
  if (part == 0) {
#pragma unroll
    for (int j = 0; j < 4; ++j) { bfa[j] = bf[tc * 4 + j]; bsa[j] = bs[tc * 4 + j]; }
  }

#pragma unroll
  for (int i = 0; i < 8; ++i) {
    int row = row0 + tr * 8 + i;
    if (row >= N) continue;
    size_t base = (size_t)row * 512 + part * 256 + tc * 8;
    float4 o0, o1;
    o0.x = accf[i][0] + bfa[0]; o0.y = accs[i][0] + bsa[0];
    o0.z = accf[i][1] + bfa[1]; o0.w = accs[i][1] + bsa[1];
    o1.x = accf[i][2] + bfa[2]; o1.y = accs[i][2] + bsa[2];
    o1.z = accf[i][3] + bfa[3]; o1.w = accs[i][3] + bsa[3];
    *(float4*)&P2[base] = o0;
    *(float4*)&P2[base + 4] = o1;
  }
}

// ---------------- edge kernel ----------------
// 256 threads = 2 edges per iteration; 128 threads (2 waves) per edge, one col each.
// W_edge rows 256:288 held per-thread in registers (64 floats) -> launch_bounds(256,3)
// gives VGPR cap ~168 so they actually stay in registers (R1 had VGPR=48 -> spilled).
__global__ __launch_bounds__(256, 3) void edge_kernel(
    const float* __restrict__ P2, const float* __restrict__ eattr,
    const float* __restrict__ Wf, const float* __restrict__ Ws,
    const int* __restrict__ src, const int* __restrict__ dst,
    float* __restrict__ agg, int E) {
  const int c = threadIdx.x & 127;
  const int half = threadIdx.x >> 7;

  float wf[NRBF], ws[NRBF];
#pragma unroll
  for (int k = 0; k < NRBF; ++k) {
    wf[k] = Wf[(size_t)(256 + k) * HID + c];
    ws[k] = Ws[(size_t)(256 + k) * HID + c];
  }

  const int npairs = E >> 1;
  for (int p = blockIdx.x; p < npairs; p += gridDim.x) {
    int e = __builtin_amdgcn_readfirstlane(p * 2 + half);  // wave-uniform
    const int s = src[e];
    const int d = dst[e];
    const float* ep = eattr + (size_t)e * NRBF;
    float af = 0.f, as = 0.f;
#pragma unroll
    for (int k = 0; k < NRBF; ++k) {
      float ev = ep[k];
      af = fmaf(ev, wf[k], af);
      as = fmaf(ev, ws[k], as);
    }
    const float2 pd = *(const float2*)&P2[(size_t)d * 512 + c * 2];        // dst: {f,s}
    const float2 ps = *(const float2*)&P2[(size_t)s * 512 + 256 + c * 2];  // src: {f,s}
    float zf = pd.x + ps.x + af;  // bf folded into P2 part 0
    float zs = pd.y + ps.y + as;  // bs folded into P2 part 0
    float sig = __builtin_amdgcn_rcpf(1.f + __expf(-zf));
    float sp = fmaxf(zs, 0.f) + __logf(1.f + __expf(-fabsf(zs)));
    atomicAdd(&agg[(size_t)d * HID + c], sig * sp);
  }
}

// ---------------- h = relu(h + agg), float4 ----------------
__global__ void relu_add(float* __restrict__ h, const float* __restrict__ agg) {
  int i = blockIdx.x * blockDim.x + threadIdx.x;
  if (i >= NNODES * 32) return;
  float4 a = *(float4*)&h[(size_t)i * 4];
  float4 b = *(const float4*)&agg[(size_t)i * 4];
  float4 o;
  o.x = fmaxf(a.x + b.x, 0.f);
  o.y = fmaxf(a.y + b.y, 0.f);
  o.z = fmaxf(a.z + b.z, 0.f);
  o.w = fmaxf(a.w + b.w, 0.f);
  *(float4*)&h[(size_t)i * 4] = o;
}

// ---------------- pooling: segment sums + counts ----------------
__global__ void pool_kernel(const float* __restrict__ h, const int* __restrict__ batch,
                            float* __restrict__ sums, float* __restrict__ counts) {
  int i = blockIdx.x * blockDim.x + threadIdx.x;
  if (i >= NNODES * HID) return;
  int node = i >> 7, c = i & 127;
  int g = batch[node];
  atomicAdd(&sums[(size_t)g * HID + c], h[i]);
  if (c == 0) atomicAdd(&counts[g], 1.f);
}

// ---------------- out[g] = (sums[g]/max(cnt,1)) @ Wlin + blin ----------------
__global__ __launch_bounds__(128) void final_kernel(
    const float* __restrict__ sums, const float* __restrict__ counts,
    const float* __restrict__ Wlin, const float* __restrict__ blin,
    float* __restrict__ out) {
  int g = blockIdx.x;
  int c = threadIdx.x;
  __shared__ float pool[HID];
  float cnt = counts[g];
  cnt = cnt > 1.f ? cnt : 1.f;
  pool[c] = sums[(size_t)g * HID + c] / cnt;
  __syncthreads();
  float acc = blin[c];
#pragma unroll 8
  for (int k = 0; k < HID; ++k) acc = fmaf(pool[k], Wlin[k * HID + c], acc);
  out[(size_t)g * HID + c] = acc;
}

extern "C" void kernel_launch(void* const* d_in, const int* in_sizes, int n_in,
                              void* d_out, int out_size, void* d_ws, size_t ws_size,
                              hipStream_t stream) {
  const int* x = (const int*)d_in[0];
  const int* eidx = (const int*)d_in[1];
  const float* eattr = (const float*)d_in[2];
  const int* batch = (const int*)d_in[3];
  const float* emb = (const float*)d_in[4];
  const float* Wf[3] = {(const float*)d_in[5], (const float*)d_in[9], (const float*)d_in[13]};
  const float* bf[3] = {(const float*)d_in[6], (const float*)d_in[10], (const float*)d_in[14]};
  const float* Ws[3] = {(const float*)d_in[7], (const float*)d_in[11], (const float*)d_in[15]};
  const float* bs[3] = {(const float*)d_in[8], (const float*)d_in[12], (const float*)d_in[16]};
  const float* Wlin = (const float*)d_in[17];
  const float* blin = (const float*)d_in[18];
  const int* srcp = eidx;
  const int* dstp = eidx + NEDGES;

  float* wsf = (float*)d_ws;
  float* h = wsf;                                  // N*128
  float* P2 = h + (size_t)NNODES * HID;            // N*512 interleaved
  float* agg = P2 + (size_t)NNODES * 512;          // N*128
  float* sums = agg + (size_t)NNODES * HID;        // 500*128
  float* counts = sums + (size_t)NGRAPH * HID;     // 500

  const int nelem = NNODES * HID;
  embed_kernel<<<(NNODES * 32 + 255) / 256, 256, 0, stream>>>(x, emb, h);

  dim3 ggrid((NNODES + 63) / 64, 2);
  for (int l = 0; l < 3; ++l) {
    hipMemsetAsync(agg, 0, (size_t)nelem * sizeof(float), stream);
    node_gemm2<<<ggrid, 256, 0, stream>>>(h, Wf[l], bf[l], Ws[l], bs[l], P2, NNODES);
    edge_kernel<<<2048, 256, 0, stream>>>(P2, eattr, Wf[l], Ws[l], srcp, dstp, agg, NEDGES);
    relu_add<<<(NNODES * 32 + 255) / 256, 256, 0, stream>>>(h, agg);
  }

  hipMemsetAsync(sums, 0, (size_t)(NGRAPH * HID + NGRAPH) * sizeof(float), stream);
  pool_kernel<<<(nelem + 255) / 256, 256, 0, stream>>>(h, batch, sums, counts);
  final_kernel<<<NGRAPH, 128, 0, stream>>>(sums, counts, Wlin, blin, (float*)d_out);
}

// Round 3
// 1939.918 us; speedup vs baseline: 1.4196x; 1.4196x over previous
//
#include <hip/hip_runtime.h>
#include <cstdint>
#include <cstddef>

#define NNODES 50000
#define NEDGES 800000
#define HID 128
#define NRBF 32
#define NGRAPH 500
#define NB_SCAN 196  // ceil(50000/256)

// ---------------- embed: h[n,c] = emb[x[n],c], float4 ----------------
__global__ void embed_kernel(const int* __restrict__ x, const float* __restrict__ emb,
                             float* __restrict__ h) {
  int i = blockIdx.x * blockDim.x + threadIdx.x;
  if (i >= NNODES * 32) return;
  int node = i >> 5, c4 = (i & 31) * 4;
  *(float4*)&h[(size_t)node * HID + c4] = *(const float4*)&emb[(size_t)x[node] * HID + c4];
}

// ---------------- CSR build: histogram -> scan -> scatter ----------------
__global__ void deg_hist(const int* __restrict__ dst, int* __restrict__ deg) {
  int e = blockIdx.x * blockDim.x + threadIdx.x;
  if (e < NEDGES) atomicAdd(&deg[dst[e]], 1);
}

__global__ __launch_bounds__(256) void scan_block(const int* __restrict__ deg, int* __restrict__ bsum) {
  __shared__ int s[256];
  int i = blockIdx.x * 256 + threadIdx.x;
  s[threadIdx.x] = (i < NNODES) ? deg[i] : 0;
  __syncthreads();
  for (int off = 128; off > 0; off >>= 1) {
    if (threadIdx.x < off) s[threadIdx.x] += s[threadIdx.x + off];
    __syncthreads();
  }
  if (threadIdx.x == 0) bsum[blockIdx.x] = s[0];
}

__global__ void scan_top(const int* __restrict__ bsum, int* __restrict__ bpre,
                         int* __restrict__ rowptr) {
  if (threadIdx.x == 0) {
    int acc = 0;
    for (int b = 0; b < NB_SCAN; ++b) { bpre[b] = acc; acc += bsum[b]; }
    rowptr[NNODES] = acc;
  }
}

__global__ __launch_bounds__(256) void scan_final(const int* __restrict__ deg,
                                                  const int* __restrict__ bpre,
                                                  int* __restrict__ rowptr,
                                                  int* __restrict__ cursor) {
  __shared__ int s[256];
  int i = blockIdx.x * 256 + threadIdx.x;
  int v = (i < NNODES) ? deg[i] : 0;
  s[threadIdx.x] = v;
  __syncthreads();
  for (int off = 1; off < 256; off <<= 1) {
    int t = (threadIdx.x >= off) ? s[threadIdx.x - off] : 0;
    __syncthreads();
    s[threadIdx.x] += t;
    __syncthreads();
  }
  if (i < NNODES) {
    int ex = bpre[blockIdx.x] + s[threadIdx.x] - v;  // exclusive
    rowptr[i] = ex;
    cursor[i] = ex;
  }
}

__global__ void scatter_edges(const int* __restrict__ dst, int* __restrict__ cursor,
                              int* __restrict__ perm) {
  int e = blockIdx.x * blockDim.x + threadIdx.x;
  if (e < NEDGES) {
    int pos = atomicAdd(&cursor[dst[e]], 1);
    perm[pos] = e;
  }
}

// ---------------- node GEMM (R1 structure): P = h @ [Wf_d|Wf_s|Ws_d|Ws_s] ----------------
__global__ __launch_bounds__(256) void node_gemm(
    const float* __restrict__ h, const float* __restrict__ Wf,
    const float* __restrict__ bf, const float* __restrict__ Ws,
    const float* __restrict__ bs, float* __restrict__ P, int N) {
  const int part = blockIdx.y;  // 0: Wf[0:128]+bf, 1: Wf[128:256], 2: Ws[0:128]+bs, 3: Ws[128:256]
  const int row0 = blockIdx.x * 128;
  const float* W = ((part < 2) ? Wf : Ws) + ((part & 1) ? (128 * HID) : 0);
  const float* bias = (part == 0) ? bf : ((part == 2) ? bs : nullptr);

  __shared__ __align__(16) float hsT[32][132];
  __shared__ __align__(16) float wsm[32][132];

  const int tc = threadIdx.x & 15;
  const int tr = threadIdx.x >> 4;

  float acc[8][8];
#pragma unroll
  for (int i = 0; i < 8; ++i)
#pragma unroll
    for (int j = 0; j < 8; ++j) acc[i][j] = 0.f;

  for (int kc = 0; kc < HID; kc += 32) {
#pragma unroll
    for (int j = 0; j < 4; ++j) {
      int i = threadIdx.x + 256 * j;
      int node = i >> 3;
      int kq = i & 7;
      int grow = row0 + node;
      if (grow >= N) grow = N - 1;
      const float4 v = *(const float4*)&h[(size_t)grow * HID + kc + kq * 4];
      hsT[kq * 4 + 0][node] = v.x;
      hsT[kq * 4 + 1][node] = v.y;
      hsT[kq * 4 + 2][node] = v.z;
      hsT[kq * 4 + 3][node] = v.w;
    }
#pragma unroll
    for (int j = 0; j < 4; ++j) {
      int i = threadIdx.x + 256 * j;
      int kk = i >> 5;
      int colq = i & 31;
      *(float4*)&wsm[kk][colq * 4] = *(const float4*)&W[(size_t)(kc + kk) * HID + colq * 4];
    }
    __syncthreads();
#pragma unroll
    for (int k = 0; k < 32; ++k) {
      float4 a0 = *(const float4*)&hsT[k][tr * 8];
      float4 a1 = *(const float4*)&hsT[k][tr * 8 + 4];
      float4 b0 = *(const float4*)&wsm[k][tc * 4];
      float4 b1 = *(const float4*)&wsm[k][tc * 4 + 64];
      float av[8] = {a0.x, a0.y, a0.z, a0.w, a1.x, a1.y, a1.z, a1.w};
      float bv[8] = {b0.x, b0.y, b0.z, b0.w, b1.x, b1.y, b1.z, b1.w};
#pragma unroll
      for (int i = 0; i < 8; ++i)
#pragma unroll
        for (int jj = 0; jj < 8; ++jj) acc[i][jj] += av[i] * bv[jj];
    }
    __syncthreads();
  }

  float badd[8];
#pragma unroll
  for (int half = 0; half < 2; ++half)
#pragma unroll
    for (int u = 0; u < 4; ++u)
      badd[half * 4 + u] = bias ? bias[half * 64 + tc * 4 + u] : 0.f;

  const int colBase = part * HID;
#pragma unroll
  for (int i = 0; i < 8; ++i) {
    int row = row0 + tr * 8 + i;
    if (row >= N) continue;
#pragma unroll
    for (int half = 0; half < 2; ++half) {
      float4 o;
      o.x = acc[i][half * 4 + 0] + badd[half * 4 + 0];
      o.y = acc[i][half * 4 + 1] + badd[half * 4 + 1];
      o.z = acc[i][half * 4 + 2] + badd[half * 4 + 2];
      o.w = acc[i][half * 4 + 3] + badd[half * 4 + 3];
      *(float4*)&P[(size_t)row * 512 + colBase + half * 64 + tc * 4] = o;
    }
  }
}

// ---------------- CSR edge kernel: per-dst team, register accumulation, fused relu ----
// 256 threads = 2 teams of 128; team processes dst nodes grid-stride.
// No stores in the inner loop -> weight loads are loop-invariant and hoistable.
__global__ __launch_bounds__(256, 3) void edge_csr(
    const float* __restrict__ P, const float* __restrict__ eattr,
    const float* __restrict__ Wf, const float* __restrict__ Ws,
    const int* __restrict__ src, const int* __restrict__ perm,
    const int* __restrict__ rowptr, float* __restrict__ h) {
  const int c = threadIdx.x & 127;
  const int team = (blockIdx.x << 1) | (threadIdx.x >> 7);
  const int nteams = gridDim.x << 1;

  float wfr[NRBF], wsr[NRBF];
#pragma unroll
  for (int k = 0; k < NRBF; ++k) {
    wfr[k] = Wf[(size_t)(256 + k) * HID + c];
    wsr[k] = Ws[(size_t)(256 + k) * HID + c];
  }

  for (int d = team; d < NNODES; d += nteams) {
    const int beg = rowptr[d];
    const int end = rowptr[d + 1];
    const float pdf = P[(size_t)d * 512 + c];        // Wf dst proj (+bf)
    const float pds = P[(size_t)d * 512 + 256 + c];  // Ws dst proj (+bs)
    float accm = 0.f;
    for (int j = beg; j < end; ++j) {
      int e = __builtin_amdgcn_readfirstlane(perm[j]);
      int s = __builtin_amdgcn_readfirstlane(src[e]);
      const float* ep = eattr + (size_t)e * NRBF;
      float af = 0.f, as = 0.f;
#pragma unroll
      for (int k = 0; k < NRBF; ++k) {
        float ev = ep[k];
        af = fmaf(ev, wfr[k], af);
        as = fmaf(ev, wsr[k], as);
      }
      const float psf = P[(size_t)s * 512 + 128 + c];
      const float pss = P[(size_t)s * 512 + 384 + c];
      float zf = pdf + psf + af;
      float zs = pds + pss + as;
      float sig = 1.f / (1.f + __expf(-zf));
      float sp = fmaxf(zs, 0.f) + __logf(1.f + __expf(-fabsf(zs)));
      accm = fmaf(sig, sp, accm);
    }
    float hv = h[(size_t)d * HID + c] + accm;
    h[(size_t)d * HID + c] = fmaxf(hv, 0.f);
  }
}

// ---------------- pooling: segment sums + counts ----------------
__global__ void pool_kernel(const float* __restrict__ h, const int* __restrict__ batch,
                            float* __restrict__ sums, float* __restrict__ counts) {
  int i = blockIdx.x * blockDim.x + threadIdx.x;
  if (i >= NNODES * HID) return;
  int node = i >> 7, c = i & 127;
  int g = batch[node];
  atomicAdd(&sums[(size_t)g * HID + c], h[i]);
  if (c == 0) atomicAdd(&counts[g], 1.f);
}

// ---------------- out[g] = (sums[g]/max(cnt,1)) @ Wlin + blin ----------------
__global__ __launch_bounds__(128) void final_kernel(
    const float* __restrict__ sums, const float* __restrict__ counts,
    const float* __restrict__ Wlin, const float* __restrict__ blin,
    float* __restrict__ out) {
  int g = blockIdx.x;
  int c = threadIdx.x;
  __shared__ float pool[HID];
  float cnt = counts[g];
  cnt = cnt > 1.f ? cnt : 1.f;
  pool[c] = sums[(size_t)g * HID + c] / cnt;
  __syncthreads();
  float acc = blin[c];
#pragma unroll 8
  for (int k = 0; k < HID; ++k) acc = fmaf(pool[k], Wlin[k * HID + c], acc);
  out[(size_t)g * HID + c] = acc;
}

extern "C" void kernel_launch(void* const* d_in, const int* in_sizes, int n_in,
                              void* d_out, int out_size, void* d_ws, size_t ws_size,
                              hipStream_t stream) {
  const int* x = (const int*)d_in[0];
  const int* eidx = (const int*)d_in[1];
  const float* eattr = (const float*)d_in[2];
  const int* batch = (const int*)d_in[3];
  const float* emb = (const float*)d_in[4];
  const float* Wf[3] = {(const float*)d_in[5], (const float*)d_in[9], (const float*)d_in[13]};
  const float* bf[3] = {(const float*)d_in[6], (const float*)d_in[10], (const float*)d_in[14]};
  const float* Ws[3] = {(const float*)d_in[7], (const float*)d_in[11], (const float*)d_in[15]};
  const float* bs[3] = {(const float*)d_in[8], (const float*)d_in[12], (const float*)d_in[16]};
  const float* Wlin = (const float*)d_in[17];
  const float* blin = (const float*)d_in[18];
  const int* srcp = eidx;
  const int* dstp = eidx + NEDGES;

  float* wsf = (float*)d_ws;
  float* h = wsf;                                  // N*128
  float* P = h + (size_t)NNODES * HID;             // N*512
  float* sums = P + (size_t)NNODES * 512;          // 500*128
  float* counts = sums + (size_t)NGRAPH * HID;     // 500
  int* ibase = (int*)(counts + NGRAPH);
  int* deg = ibase;                                // 50000
  int* rowptr = deg + NNODES;                      // 50001
  int* cursor = rowptr + NNODES + 1;               // 50000
  int* perm = cursor + NNODES;                     // 800000
  int* bsum = perm + NEDGES;                       // 196
  int* bpre = bsum + NB_SCAN;                      // 196

  // --- CSR build (edges are layer-invariant: build once per call) ---
  hipMemsetAsync(deg, 0, NNODES * sizeof(int), stream);
  deg_hist<<<(NEDGES + 255) / 256, 256, 0, stream>>>(dstp, deg);
  scan_block<<<NB_SCAN, 256, 0, stream>>>(deg, bsum);
  scan_top<<<1, 64, 0, stream>>>(bsum, bpre, rowptr);
  scan_final<<<NB_SCAN, 256, 0, stream>>>(deg, bpre, rowptr, cursor);
  scatter_edges<<<(NEDGES + 255) / 256, 256, 0, stream>>>(dstp, cursor, perm);

  embed_kernel<<<(NNODES * 32 + 255) / 256, 256, 0, stream>>>(x, emb, h);

  dim3 ggrid((NNODES + 127) / 128, 4);
  for (int l = 0; l < 3; ++l) {
    node_gemm<<<ggrid, 256, 0, stream>>>(h, Wf[l], bf[l], Ws[l], bs[l], P, NNODES);
    edge_csr<<<1024, 256, 0, stream>>>(P, eattr, Wf[l], Ws[l], srcp, perm, rowptr, h);
  }

  hipMemsetAsync(sums, 0, (size_t)(NGRAPH * HID + NGRAPH) * sizeof(float), stream);
  pool_kernel<<<(NNODES * HID + 255) / 256, 256, 0, stream>>>(h, batch, sums, counts);
  final_kernel<<<NGRAPH, 128, 0, stream>>>(sums, counts, Wlin, blin, (float*)d_out);
}

// Round 4
// 1714.166 us; speedup vs baseline: 1.6066x; 1.1317x over previous
//
#include <hip/hip_runtime.h>
#include <cstdint>
#include <cstddef>

#define NNODES 50000
#define NEDGES 800000
#define HID 128
#define NRBF 32
#define NGRAPH 500
#define NB_SCAN 196  // ceil(50000/256)

// ---------------- embed: h[n,c] = emb[x[n],c], float4 ----------------
__global__ void embed_kernel(const int* __restrict__ x, const float* __restrict__ emb,
                             float* __restrict__ h) {
  int i = blockIdx.x * blockDim.x + threadIdx.x;
  if (i >= NNODES * 32) return;
  int node = i >> 5, c4 = (i & 31) * 4;
  *(float4*)&h[(size_t)node * HID + c4] = *(const float4*)&emb[(size_t)x[node] * HID + c4];
}

// ---------------- CSR build: histogram -> scan -> scatter {src,e} ----------------
__global__ void deg_hist(const int* __restrict__ dst, int* __restrict__ deg) {
  int e = blockIdx.x * blockDim.x + threadIdx.x;
  if (e < NEDGES) atomicAdd(&deg[dst[e]], 1);
}

__global__ __launch_bounds__(256) void scan_block(const int* __restrict__ deg, int* __restrict__ bsum) {
  __shared__ int s[256];
  int i = blockIdx.x * 256 + threadIdx.x;
  s[threadIdx.x] = (i < NNODES) ? deg[i] : 0;
  __syncthreads();
  for (int off = 128; off > 0; off >>= 1) {
    if (threadIdx.x < off) s[threadIdx.x] += s[threadIdx.x + off];
    __syncthreads();
  }
  if (threadIdx.x == 0) bsum[blockIdx.x] = s[0];
}

__global__ void scan_top(const int* __restrict__ bsum, int* __restrict__ bpre,
                         int* __restrict__ rowptr) {
  if (threadIdx.x == 0) {
    int acc = 0;
    for (int b = 0; b < NB_SCAN; ++b) { bpre[b] = acc; acc += bsum[b]; }
    rowptr[NNODES] = acc;
  }
}

__global__ __launch_bounds__(256) void scan_final(const int* __restrict__ deg,
                                                  const int* __restrict__ bpre,
                                                  int* __restrict__ rowptr,
                                                  int* __restrict__ cursor) {
  __shared__ int s[256];
  int i = blockIdx.x * 256 + threadIdx.x;
  int v = (i < NNODES) ? deg[i] : 0;
  s[threadIdx.x] = v;
  __syncthreads();
  for (int off = 1; off < 256; off <<= 1) {
    int t = (threadIdx.x >= off) ? s[threadIdx.x - off] : 0;
    __syncthreads();
    s[threadIdx.x] += t;
    __syncthreads();
  }
  if (i < NNODES) {
    int ex = bpre[blockIdx.x] + s[threadIdx.x] - v;  // exclusive
    rowptr[i] = ex;
    cursor[i] = ex;
  }
}

__global__ void scatter_edges(const int* __restrict__ src, const int* __restrict__ dst,
                              int* __restrict__ cursor, int2* __restrict__ se) {
  int e = blockIdx.x * blockDim.x + threadIdx.x;
  if (e < NEDGES) {
    int pos = atomicAdd(&cursor[dst[e]], 1);
    se[pos] = make_int2(src[e], e);
  }
}

// ---------------- node GEMM: P = h @ [Wf_d|Wf_s|Ws_d|Ws_s] ----------------
__global__ __launch_bounds__(256) void node_gemm(
    const float* __restrict__ h, const float* __restrict__ Wf,
    const float* __restrict__ bf, const float* __restrict__ Ws,
    const float* __restrict__ bs, float* __restrict__ P, int N) {
  const int part = blockIdx.y;  // 0: Wf[0:128]+bf, 1: Wf[128:256], 2: Ws[0:128]+bs, 3: Ws[128:256]
  const int row0 = blockIdx.x * 128;
  const float* W = ((part < 2) ? Wf : Ws) + ((part & 1) ? (128 * HID) : 0);
  const float* bias = (part == 0) ? bf : ((part == 2) ? bs : nullptr);

  __shared__ __align__(16) float hsT[32][132];
  __shared__ __align__(16) float wsm[32][132];

  const int tc = threadIdx.x & 15;
  const int tr = threadIdx.x >> 4;

  float acc[8][8];
#pragma unroll
  for (int i = 0; i < 8; ++i)
#pragma unroll
    for (int j = 0; j < 8; ++j) acc[i][j] = 0.f;

  for (int kc = 0; kc < HID; kc += 32) {
#pragma unroll
    for (int j = 0; j < 4; ++j) {
      int i = threadIdx.x + 256 * j;
      int node = i >> 3;
      int kq = i & 7;
      int grow = row0 + node;
      if (grow >= N) grow = N - 1;
      const float4 v = *(const float4*)&h[(size_t)grow * HID + kc + kq * 4];
      hsT[kq * 4 + 0][node] = v.x;
      hsT[kq * 4 + 1][node] = v.y;
      hsT[kq * 4 + 2][node] = v.z;
      hsT[kq * 4 + 3][node] = v.w;
    }
#pragma unroll
    for (int j = 0; j < 4; ++j) {
      int i = threadIdx.x + 256 * j;
      int kk = i >> 5;
      int colq = i & 31;
      *(float4*)&wsm[kk][colq * 4] = *(const float4*)&W[(size_t)(kc + kk) * HID + colq * 4];
    }
    __syncthreads();
#pragma unroll
    for (int k = 0; k < 32; ++k) {
      float4 a0 = *(const float4*)&hsT[k][tr * 8];
      float4 a1 = *(const float4*)&hsT[k][tr * 8 + 4];
      float4 b0 = *(const float4*)&wsm[k][tc * 4];
      float4 b1 = *(const float4*)&wsm[k][tc * 4 + 64];
      float av[8] = {a0.x, a0.y, a0.z, a0.w, a1.x, a1.y, a1.z, a1.w};
      float bv[8] = {b0.x, b0.y, b0.z, b0.w, b1.x, b1.y, b1.z, b1.w};
#pragma unroll
      for (int i = 0; i < 8; ++i)
#pragma unroll
        for (int jj = 0; jj < 8; ++jj) acc[i][jj] += av[i] * bv[jj];
    }
    __syncthreads();
  }

  float badd[8];
#pragma unroll
  for (int half = 0; half < 2; ++half)
#pragma unroll
    for (int u = 0; u < 4; ++u)
      badd[half * 4 + u] = bias ? bias[half * 64 + tc * 4 + u] : 0.f;

  const int colBase = part * HID;
#pragma unroll
  for (int i = 0; i < 8; ++i) {
    int row = row0 + tr * 8 + i;
    if (row >= N) continue;
#pragma unroll
    for (int half = 0; half < 2; ++half) {
      float4 o;
      o.x = acc[i][half * 4 + 0] + badd[half * 4 + 0];
      o.y = acc[i][half * 4 + 1] + badd[half * 4 + 1];
      o.z = acc[i][half * 4 + 2] + badd[half * 4 + 2];
      o.w = acc[i][half * 4 + 3] + badd[half * 4 + 3];
      *(float4*)&P[(size_t)row * 512 + colBase + half * 64 + tc * 4] = o;
    }
  }
}

// ---------------- CSR edge kernel ----------------
// Team = 128 threads (2 waves) per dst. dst id forced wave-uniform via readfirstlane
// so rowptr/se/eattr loads are uniform -> SMEM (s_load), and the 64 per-thread
// edge-weight registers survive thanks to waves_per_eu(4,4) (VGPR budget 128;
// R3's launch_bounds(256,3) still let the allocator target 8 waves -> spill).
__global__ __launch_bounds__(256)
__attribute__((amdgpu_waves_per_eu(4, 4)))
void edge_csr(
    const float* __restrict__ P, const float* __restrict__ eattr,
    const float* __restrict__ Wf, const float* __restrict__ Ws,
    const int2* __restrict__ se, const int* __restrict__ rowptr,
    float* __restrict__ h) {
  const int c = threadIdx.x & 127;
  const int team = __builtin_amdgcn_readfirstlane((blockIdx.x << 1) | (threadIdx.x >> 7));
  const int nteams = gridDim.x << 1;

  float wfr[NRBF], wsr[NRBF];
#pragma unroll
  for (int k = 0; k < NRBF; ++k) {
    wfr[k] = Wf[(size_t)(256 + k) * HID + c];
    wsr[k] = Ws[(size_t)(256 + k) * HID + c];
  }

  for (int d = team; d < NNODES; d += nteams) {
    const int beg = rowptr[d];
    const int end = rowptr[d + 1];
    const float pdf = P[(size_t)d * 512 + c];        // Wf dst proj (+bf)
    const float pds = P[(size_t)d * 512 + 256 + c];  // Ws dst proj (+bs)
    float accm = 0.f;
    for (int j = beg; j < end; ++j) {
      const int2 sej = se[j];  // uniform address -> s_load_dwordx2
      const int s = __builtin_amdgcn_readfirstlane(sej.x);
      const int e = __builtin_amdgcn_readfirstlane(sej.y);
      const float* ep = eattr + (size_t)e * NRBF;  // uniform -> s_load_dwordx16
      float af = 0.f, as = 0.f;
#pragma unroll
      for (int k = 0; k < NRBF; ++k) {
        float ev = ep[k];
        af = fmaf(ev, wfr[k], af);
        as = fmaf(ev, wsr[k], as);
      }
      const float psf = P[(size_t)s * 512 + 128 + c];
      const float pss = P[(size_t)s * 512 + 384 + c];
      float zf = pdf + psf + af;
      float zs = pds + pss + as;
      float sig = 1.f / (1.f + __expf(-zf));
      float sp = fmaxf(zs, 0.f) + __logf(1.f + __expf(-fabsf(zs)));
      accm = fmaf(sig, sp, accm);
    }
    float hv = h[(size_t)d * HID + c] + accm;
    h[(size_t)d * HID + c] = fmaxf(hv, 0.f);  // fused relu(h + agg)
  }
}

// ---------------- pooling: segment sums + counts ----------------
__global__ void pool_kernel(const float* __restrict__ h, const int* __restrict__ batch,
                            float* __restrict__ sums, float* __restrict__ counts) {
  int i = blockIdx.x * blockDim.x + threadIdx.x;
  if (i >= NNODES * HID) return;
  int node = i >> 7, c = i & 127;
  int g = batch[node];
  atomicAdd(&sums[(size_t)g * HID + c], h[i]);
  if (c == 0) atomicAdd(&counts[g], 1.f);
}

// ---------------- out[g] = (sums[g]/max(cnt,1)) @ Wlin + blin ----------------
__global__ __launch_bounds__(128) void final_kernel(
    const float* __restrict__ sums, const float* __restrict__ counts,
    const float* __restrict__ Wlin, const float* __restrict__ blin,
    float* __restrict__ out) {
  int g = blockIdx.x;
  int c = threadIdx.x;
  __shared__ float pool[HID];
  float cnt = counts[g];
  cnt = cnt > 1.f ? cnt : 1.f;
  pool[c] = sums[(size_t)g * HID + c] / cnt;
  __syncthreads();
  float acc = blin[c];
#pragma unroll 8
  for (int k = 0; k < HID; ++k) acc = fmaf(pool[k], Wlin[k * HID + c], acc);
  out[(size_t)g * HID + c] = acc;
}

extern "C" void kernel_launch(void* const* d_in, const int* in_sizes, int n_in,
                              void* d_out, int out_size, void* d_ws, size_t ws_size,
                              hipStream_t stream) {
  const int* x = (const int*)d_in[0];
  const int* eidx = (const int*)d_in[1];
  const float* eattr = (const float*)d_in[2];
  const int* batch = (const int*)d_in[3];
  const float* emb = (const float*)d_in[4];
  const float* Wf[3] = {(const float*)d_in[5], (const float*)d_in[9], (const float*)d_in[13]};
  const float* bf[3] = {(const float*)d_in[6], (const float*)d_in[10], (const float*)d_in[14]};
  const float* Ws[3] = {(const float*)d_in[7], (const float*)d_in[11], (const float*)d_in[15]};
  const float* bs[3] = {(const float*)d_in[8], (const float*)d_in[12], (const float*)d_in[16]};
  const float* Wlin = (const float*)d_in[17];
  const float* blin = (const float*)d_in[18];
  const int* srcp = eidx;
  const int* dstp = eidx + NEDGES;

  float* wsf = (float*)d_ws;
  float* h = wsf;                                  // 6.4M floats
  float* P = h + (size_t)NNODES * HID;             // 25.6M
  float* sums = P + (size_t)NNODES * 512;          // 64000
  float* counts = sums + (size_t)NGRAPH * HID;     // 500
  int2* se = (int2*)(counts + NGRAPH);             // 800000 int2 (8B-aligned: offset is 8B-multiple)
  int* ibase = (int*)(se + NEDGES);
  int* deg = ibase;                                // 50000
  int* rowptr = deg + NNODES;                      // 50001
  int* cursor = rowptr + NNODES + 1;               // 50000
  int* bsum = cursor + NNODES;                     // 196
  int* bpre = bsum + NB_SCAN;                      // 196

  // --- CSR build (edges layer-invariant: once per call) ---
  hipMemsetAsync(deg, 0, NNODES * sizeof(int), stream);
  deg_hist<<<(NEDGES + 255) / 256, 256, 0, stream>>>(dstp, deg);
  scan_block<<<NB_SCAN, 256, 0, stream>>>(deg, bsum);
  scan_top<<<1, 64, 0, stream>>>(bsum, bpre, rowptr);
  scan_final<<<NB_SCAN, 256, 0, stream>>>(deg, bpre, rowptr, cursor);
  scatter_edges<<<(NEDGES + 255) / 256, 256, 0, stream>>>(srcp, dstp, cursor, se);

  embed_kernel<<<(NNODES * 32 + 255) / 256, 256, 0, stream>>>(x, emb, h);

  dim3 ggrid((NNODES + 127) / 128, 4);
  for (int l = 0; l < 3; ++l) {
    node_gemm<<<ggrid, 256, 0, stream>>>(h, Wf[l], bf[l], Ws[l], bs[l], P, NNODES);
    edge_csr<<<1024, 256, 0, stream>>>(P, eattr, Wf[l], Ws[l], se, rowptr, h);
  }

  hipMemsetAsync(sums, 0, (size_t)(NGRAPH * HID + NGRAPH) * sizeof(float), stream);
  pool_kernel<<<(NNODES * HID + 255) / 256, 256, 0, stream>>>(h, batch, sums, counts);
  final_kernel<<<NGRAPH, 128, 0, stream>>>(sums, counts, Wlin, blin, (float*)d_out);
}

// Round 5
// 1677.621 us; speedup vs baseline: 1.6416x; 1.0218x over previous
//
#include <hip/hip_runtime.h>
#include <cstdint>
#include <cstddef>

#define NNODES 50000
#define NEDGES 800000
#define HID 128
#define NRBF 32
#define NGRAPH 500
#define NB_SCAN 196  // ceil(50000/256)

// ---------------- embed: h[n,c] = emb[x[n],c], float4 ----------------
__global__ void embed_kernel(const int* __restrict__ x, const float* __restrict__ emb,
                             float* __restrict__ h) {
  int i = blockIdx.x * blockDim.x + threadIdx.x;
  if (i >= NNODES * 32) return;
  int node = i >> 5, c4 = (i & 31) * 4;
  *(float4*)&h[(size_t)node * HID + c4] = *(const float4*)&emb[(size_t)x[node] * HID + c4];
}

// ---------------- edge-weight transpose: Wt[c][k][{f,s}], contiguous per column c ----
__global__ void transpose_wedge(const float* __restrict__ Wf, const float* __restrict__ Ws,
                                float* __restrict__ Wt) {
  int i = blockIdx.x * blockDim.x + threadIdx.x;  // 128c x 32k
  if (i >= HID * NRBF) return;
  int c = i >> 5, k = i & 31;
  Wt[c * 64 + 2 * k] = Wf[(size_t)(256 + k) * HID + c];
  Wt[c * 64 + 2 * k + 1] = Ws[(size_t)(256 + k) * HID + c];
}

// ---------------- CSR build: histogram -> scan -> scatter {src,e} ----------------
__global__ void deg_hist(const int* __restrict__ dst, int* __restrict__ deg) {
  int e = blockIdx.x * blockDim.x + threadIdx.x;
  if (e < NEDGES) atomicAdd(&deg[dst[e]], 1);
}

__global__ __launch_bounds__(256) void scan_block(const int* __restrict__ deg, int* __restrict__ bsum) {
  __shared__ int s[256];
  int i = blockIdx.x * 256 + threadIdx.x;
  s[threadIdx.x] = (i < NNODES) ? deg[i] : 0;
  __syncthreads();
  for (int off = 128; off > 0; off >>= 1) {
    if (threadIdx.x < off) s[threadIdx.x] += s[threadIdx.x + off];
    __syncthreads();
  }
  if (threadIdx.x == 0) bsum[blockIdx.x] = s[0];
}

__global__ void scan_top(const int* __restrict__ bsum, int* __restrict__ bpre,
                         int* __restrict__ rowptr) {
  if (threadIdx.x == 0) {
    int acc = 0;
    for (int b = 0; b < NB_SCAN; ++b) { bpre[b] = acc; acc += bsum[b]; }
    rowptr[NNODES] = acc;
  }
}

__global__ __launch_bounds__(256) void scan_final(const int* __restrict__ deg,
                                                  const int* __restrict__ bpre,
                                                  int* __restrict__ rowptr,
                                                  int* __restrict__ cursor) {
  __shared__ int s[256];
  int i = blockIdx.x * 256 + threadIdx.x;
  int v = (i < NNODES) ? deg[i] : 0;
  s[threadIdx.x] = v;
  __syncthreads();
  for (int off = 1; off < 256; off <<= 1) {
    int t = (threadIdx.x >= off) ? s[threadIdx.x - off] : 0;
    __syncthreads();
    s[threadIdx.x] += t;
    __syncthreads();
  }
  if (i < NNODES) {
    int ex = bpre[blockIdx.x] + s[threadIdx.x] - v;  // exclusive
    rowptr[i] = ex;
    cursor[i] = ex;
  }
}

__global__ void scatter_edges(const int* __restrict__ src, const int* __restrict__ dst,
                              int* __restrict__ cursor, int2* __restrict__ se) {
  int e = blockIdx.x * blockDim.x + threadIdx.x;
  if (e < NEDGES) {
    int pos = atomicAdd(&cursor[dst[e]], 1);
    se[pos] = make_int2(src[e], e);
  }
}

// ---------------- node GEMM: P = h @ [Wf_d|Wf_s|Ws_d|Ws_s] ----------------
__global__ __launch_bounds__(256) void node_gemm(
    const float* __restrict__ h, const float* __restrict__ Wf,
    const float* __restrict__ bf, const float* __restrict__ Ws,
    const float* __restrict__ bs, float* __restrict__ P, int N) {
  const int part = blockIdx.y;  // 0: Wf[0:128]+bf, 1: Wf[128:256], 2: Ws[0:128]+bs, 3: Ws[128:256]
  const int row0 = blockIdx.x * 128;
  const float* W = ((part < 2) ? Wf : Ws) + ((part & 1) ? (128 * HID) : 0);
  const float* bias = (part == 0) ? bf : ((part == 2) ? bs : nullptr);

  __shared__ __align__(16) float hsT[32][132];
  __shared__ __align__(16) float wsm[32][132];

  const int tc = threadIdx.x & 15;
  const int tr = threadIdx.x >> 4;

  float acc[8][8];
#pragma unroll
  for (int i = 0; i < 8; ++i)
#pragma unroll
    for (int j = 0; j < 8; ++j) acc[i][j] = 0.f;

  for (int kc = 0; kc < HID; kc += 32) {
#pragma unroll
    for (int j = 0; j < 4; ++j) {
      int i = threadIdx.x + 256 * j;
      int node = i >> 3;
      int kq = i & 7;
      int grow = row0 + node;
      if (grow >= N) grow = N - 1;
      const float4 v = *(const float4*)&h[(size_t)grow * HID + kc + kq * 4];
      hsT[kq * 4 + 0][node] = v.x;
      hsT[kq * 4 + 1][node] = v.y;
      hsT[kq * 4 + 2][node] = v.z;
      hsT[kq * 4 + 3][node] = v.w;
    }
#pragma unroll
    for (int j = 0; j < 4; ++j) {
      int i = threadIdx.x + 256 * j;
      int kk = i >> 5;
      int colq = i & 31;
      *(float4*)&wsm[kk][colq * 4] = *(const float4*)&W[(size_t)(kc + kk) * HID + colq * 4];
    }
    __syncthreads();
#pragma unroll
    for (int k = 0; k < 32; ++k) {
      float4 a0 = *(const float4*)&hsT[k][tr * 8];
      float4 a1 = *(const float4*)&hsT[k][tr * 8 + 4];
      float4 b0 = *(const float4*)&wsm[k][tc * 4];
      float4 b1 = *(const float4*)&wsm[k][tc * 4 + 64];
      float av[8] = {a0.x, a0.y, a0.z, a0.w, a1.x, a1.y, a1.z, a1.w};
      float bv[8] = {b0.x, b0.y, b0.z, b0.w, b1.x, b1.y, b1.z, b1.w};
#pragma unroll
      for (int i = 0; i < 8; ++i)
#pragma unroll
        for (int jj = 0; jj < 8; ++jj) acc[i][jj] += av[i] * bv[jj];
    }
    __syncthreads();
  }

  float badd[8];
#pragma unroll
  for (int half = 0; half < 2; ++half)
#pragma unroll
    for (int u = 0; u < 4; ++u)
      badd[half * 4 + u] = bias ? bias[half * 64 + tc * 4 + u] : 0.f;

  const int colBase = part * HID;
#pragma unroll
  for (int i = 0; i < 8; ++i) {
    int row = row0 + tr * 8 + i;
    if (row >= N) continue;
#pragma unroll
    for (int half = 0; half < 2; ++half) {
      float4 o;
      o.x = acc[i][half * 4 + 0] + badd[half * 4 + 0];
      o.y = acc[i][half * 4 + 1] + badd[half * 4 + 1];
      o.z = acc[i][half * 4 + 2] + badd[half * 4 + 2];
      o.w = acc[i][half * 4 + 3] + badd[half * 4 + 3];
      *(float4*)&P[(size_t)row * 512 + colBase + half * 64 + tc * 4] = o;
    }
  }
}

// ---------------- CSR edge kernel ----------------
// Team = 128 threads (2 waves) per dst. Per-thread edge weights loaded once as
// 16 float4 from the transposed buffer, then PINNED in VGPRs with empty inline
// asm (the load result becomes an asm output -> not rematerializable -> the
// sinking heuristic that kept re-loading them in R2-R4 can't fire).
__global__ __launch_bounds__(256)
__attribute__((amdgpu_waves_per_eu(4, 4)))
void edge_csr(
    const float* __restrict__ P, const float* __restrict__ eattr,
    const float4* __restrict__ Wt4, const int2* __restrict__ se,
    const int* __restrict__ rowptr, float* __restrict__ h) {
  const int c = threadIdx.x & 127;
  const int team = __builtin_amdgcn_readfirstlane((blockIdx.x << 1) | (threadIdx.x >> 7));
  const int nteams = gridDim.x << 1;

  float wf[NRBF], ws[NRBF];
#pragma unroll
  for (int q = 0; q < 16; ++q) {
    float4 v = Wt4[c * 16 + q];
    wf[2 * q] = v.x;
    ws[2 * q] = v.y;
    wf[2 * q + 1] = v.z;
    ws[2 * q + 1] = v.w;
  }
#pragma unroll
  for (int k = 0; k < NRBF; ++k) {
    asm volatile("" : "+v"(wf[k]), "+v"(ws[k]));  // pin in VGPRs
  }

  for (int d = team; d < NNODES; d += nteams) {
    const int beg = rowptr[d];
    const int end = rowptr[d + 1];
    const float pdf = P[(size_t)d * 512 + c];        // Wf dst proj (+bf)
    const float pds = P[(size_t)d * 512 + 256 + c];  // Ws dst proj (+bs)
    float accm = 0.f;
    for (int j = beg; j < end; ++j) {
      const int2 sej = se[j];  // uniform -> s_load
      const int s = __builtin_amdgcn_readfirstlane(sej.x);
      const int e = __builtin_amdgcn_readfirstlane(sej.y);
      const float* ep = eattr + (size_t)e * NRBF;  // uniform -> s_load_dwordx16
      float af = 0.f, as = 0.f;
#pragma unroll
      for (int k = 0; k < NRBF; ++k) {
        float ev = ep[k];
        af = fmaf(ev, wf[k], af);
        as = fmaf(ev, ws[k], as);
      }
      const float psf = P[(size_t)s * 512 + 128 + c];
      const float pss = P[(size_t)s * 512 + 384 + c];
      float zf = pdf + psf + af;
      float zs = pds + pss + as;
      float sig = __builtin_amdgcn_rcpf(1.f + __expf(-zf));
      float sp = fmaxf(zs, 0.f) + __logf(1.f + __expf(-fabsf(zs)));
      accm = fmaf(sig, sp, accm);
    }
    float hv = h[(size_t)d * HID + c] + accm;
    h[(size_t)d * HID + c] = fmaxf(hv, 0.f);  // fused relu(h + agg)
  }
}

// ---------------- pooling: segment sums + counts ----------------
__global__ void pool_kernel(const float* __restrict__ h, const int* __restrict__ batch,
                            float* __restrict__ sums, float* __restrict__ counts) {
  int i = blockIdx.x * blockDim.x + threadIdx.x;
  if (i >= NNODES * HID) return;
  int node = i >> 7, c = i & 127;
  int g = batch[node];
  atomicAdd(&sums[(size_t)g * HID + c], h[i]);
  if (c == 0) atomicAdd(&counts[g], 1.f);
}

// ---------------- out[g] = (sums[g]/max(cnt,1)) @ Wlin + blin ----------------
__global__ __launch_bounds__(128) void final_kernel(
    const float* __restrict__ sums, const float* __restrict__ counts,
    const float* __restrict__ Wlin, const float* __restrict__ blin,
    float* __restrict__ out) {
  int g = blockIdx.x;
  int c = threadIdx.x;
  __shared__ float pool[HID];
  float cnt = counts[g];
  cnt = cnt > 1.f ? cnt : 1.f;
  pool[c] = sums[(size_t)g * HID + c] / cnt;
  __syncthreads();
  float acc = blin[c];
#pragma unroll 8
  for (int k = 0; k < HID; ++k) acc = fmaf(pool[k], Wlin[k * HID + c], acc);
  out[(size_t)g * HID + c] = acc;
}

extern "C" void kernel_launch(void* const* d_in, const int* in_sizes, int n_in,
                              void* d_out, int out_size, void* d_ws, size_t ws_size,
                              hipStream_t stream) {
  const int* x = (const int*)d_in[0];
  const int* eidx = (const int*)d_in[1];
  const float* eattr = (const float*)d_in[2];
  const int* batch = (const int*)d_in[3];
  const float* emb = (const float*)d_in[4];
  const float* Wf[3] = {(const float*)d_in[5], (const float*)d_in[9], (const float*)d_in[13]};
  const float* bf[3] = {(const float*)d_in[6], (const float*)d_in[10], (const float*)d_in[14]};
  const float* Ws[3] = {(const float*)d_in[7], (const float*)d_in[11], (const float*)d_in[15]};
  const float* bs[3] = {(const float*)d_in[8], (const float*)d_in[12], (const float*)d_in[16]};
  const float* Wlin = (const float*)d_in[17];
  const float* blin = (const float*)d_in[18];
  const int* srcp = eidx;
  const int* dstp = eidx + NEDGES;

  float* wsf = (float*)d_ws;
  float* Wt = wsf;                                 // 128*64 = 8192 floats (16B-aligned base)
  float* h = Wt + 8192;                            // N*128
  float* P = h + (size_t)NNODES * HID;             // N*512
  float* sums = P + (size_t)NNODES * 512;          // 500*128
  float* counts = sums + (size_t)NGRAPH * HID;     // 500
  int2* se = (int2*)(counts + NGRAPH);             // 800000 int2
  int* ibase = (int*)(se + NEDGES);
  int* deg = ibase;                                // 50000
  int* rowptr = deg + NNODES;                      // 50001
  int* cursor = rowptr + NNODES + 1;               // 50000
  int* bsum = cursor + NNODES;                     // 196
  int* bpre = bsum + NB_SCAN;                      // 196

  // --- CSR build (edges layer-invariant: once per call) ---
  hipMemsetAsync(deg, 0, NNODES * sizeof(int), stream);
  deg_hist<<<(NEDGES + 255) / 256, 256, 0, stream>>>(dstp, deg);
  scan_block<<<NB_SCAN, 256, 0, stream>>>(deg, bsum);
  scan_top<<<1, 64, 0, stream>>>(bsum, bpre, rowptr);
  scan_final<<<NB_SCAN, 256, 0, stream>>>(deg, bpre, rowptr, cursor);
  scatter_edges<<<(NEDGES + 255) / 256, 256, 0, stream>>>(srcp, dstp, cursor, se);

  embed_kernel<<<(NNODES * 32 + 255) / 256, 256, 0, stream>>>(x, emb, h);

  dim3 ggrid((NNODES + 127) / 128, 4);
  for (int l = 0; l < 3; ++l) {
    transpose_wedge<<<(HID * NRBF + 255) / 256, 256, 0, stream>>>(Wf[l], Ws[l], Wt);
    node_gemm<<<ggrid, 256, 0, stream>>>(h, Wf[l], bf[l], Ws[l], bs[l], P, NNODES);
    edge_csr<<<1024, 256, 0, stream>>>(P, eattr, (const float4*)Wt, se, rowptr, h);
  }

  hipMemsetAsync(sums, 0, (size_t)(NGRAPH * HID + NGRAPH) * sizeof(float), stream);
  pool_kernel<<<(NNODES * HID + 255) / 256, 256, 0, stream>>>(h, batch, sums, counts);
  final_kernel<<<NGRAPH, 128, 0, stream>>>(sums, counts, Wlin, blin, (float*)d_out);
}